// Round 8
// baseline (318.570 us; speedup 1.0000x reference)
//
#include <hip/hip_runtime.h>

// out[b,i,d] = squash_d( sum_{j,k} X[b,j,d] * W[i,j,k,d] )
// B=128, I=64, J=32, K=16, D=1024.
// SETTLED dtype model (r7 on-device ballot sniff): X fp32, W fp32 — and
// therefore out fp32 per the reference (fp32 einsum+squash) and harness
// contract. r2-4's container failures were a correlated infra outage, not
// OOB faults (this source is in-bounds everywhere: W max elem 33554431,
// out max elem 8388607, ws usage 8 MiB proven to fit in r6).
// r5-7's 0.1479 = sqrt(2)*max|ref| was bf16-packed output read as fp32.
// Algebraic reduction: X doesn't depend on k ->
//   Wsum[i,j,d] = sum_k W[i,j,k,d]  (fp32, 8 MiB in d_ws)
//   s[b,i,d] = sum_j X[b,j,d]*Wsum[i,j,d]; squash over d; fp32 store.
// Traffic floor ~195 MB -> ~31 us at 6.3 TB/s.

constexpr int B_SZ = 128, I_CH = 64, J_CH = 32, K_CAP = 16, D_DIM = 1024;

// Kernel A: Wsum[i,j,d] = sum_k W[i,j,k,d].  W fp32 [I,J,K,D] -> Wsum fp32 [I,J,D].
// One thread per 4 consecutive d (float4). Fully coalesced.
__global__ __launch_bounds__(256) void wsum_k(const float* __restrict__ W,
                                              float* __restrict__ Wsum) {
    int idx = blockIdx.x * 256 + threadIdx.x;   // over IJ * (D/4) = 2048*256
    int d4 = idx & 255;                          // which float4 within D
    int ij = idx >> 8;                           // 0..2047
    const float4* Wv = (const float4*)(W + (size_t)ij * K_CAP * D_DIM) + d4;
    float4 acc = make_float4(0.f, 0.f, 0.f, 0.f);
#pragma unroll
    for (int k = 0; k < K_CAP; ++k) {
        float4 w = Wv[k * (D_DIM / 4)];
        acc.x += w.x; acc.y += w.y; acc.z += w.z; acc.w += w.w;
    }
    ((float4*)(Wsum + (size_t)ij * D_DIM))[d4] = acc;
}

// Kernel B: one block per (b,i). 128 threads, each owns 8 consecutive d.
// s[d] = sum_j X[b,j,d]*Wsum[i,j,d]; block-reduce sum(s^2) -> squash scale -> fp32 out.
__global__ __launch_bounds__(128) void caps_k(const float* __restrict__ X,
                                              const float* __restrict__ Wsum,
                                              float* __restrict__ out) {
    int i = blockIdx.x & (I_CH - 1);   // consecutive blocks share b -> L2 reuse of X slice
    int b = blockIdx.x >> 6;
    int t = threadIdx.x;               // 0..127
    const float4* Xv = (const float4*)(X + (size_t)b * J_CH * D_DIM) + 2 * t;      // stride D/4 per j
    const float4* Wv = (const float4*)(Wsum + (size_t)i * J_CH * D_DIM) + 2 * t;   // stride D/4 per j

    float s[8] = {0,0,0,0,0,0,0,0};
#pragma unroll 8
    for (int j = 0; j < J_CH; ++j) {
        float4 x0 = Xv[j * (D_DIM / 4)];
        float4 x1 = Xv[j * (D_DIM / 4) + 1];
        float4 w0 = Wv[j * (D_DIM / 4)];
        float4 w1 = Wv[j * (D_DIM / 4) + 1];
        s[0] += x0.x * w0.x;  s[1] += x0.y * w0.y;
        s[2] += x0.z * w0.z;  s[3] += x0.w * w0.w;
        s[4] += x1.x * w1.x;  s[5] += x1.y * w1.y;
        s[6] += x1.z * w1.z;  s[7] += x1.w * w1.w;
    }

    // sum of squares across the block (1024 d-values total)
    float ss = 0.f;
#pragma unroll
    for (int q = 0; q < 8; ++q) ss += s[q] * s[q];
#pragma unroll
    for (int off = 32; off > 0; off >>= 1) ss += __shfl_down(ss, off, 64);

    __shared__ float part[2];
    __shared__ float scale_sh;
    if ((t & 63) == 0) part[t >> 6] = ss;
    __syncthreads();
    if (t == 0) {
        float n2 = part[0] + part[1];
        float n  = sqrtf(n2);
        scale_sh = n2 / (1.0f + n2) / (n + 1e-8f);
    }
    __syncthreads();
    float scale = scale_sh;

    float4* Ov = (float4*)(out + ((size_t)b * I_CH + i) * D_DIM) + 2 * t;
    Ov[0] = make_float4(s[0] * scale, s[1] * scale, s[2] * scale, s[3] * scale);
    Ov[1] = make_float4(s[4] * scale, s[5] * scale, s[6] * scale, s[7] * scale);
}

extern "C" void kernel_launch(void* const* d_in, const int* in_sizes, int n_in,
                              void* d_out, int out_size, void* d_ws, size_t ws_size,
                              hipStream_t stream) {
    const float* X = (const float*)d_in[0];   // [B,J,D] fp32
    const float* W = (const float*)d_in[1];   // [I,J,K,D] fp32
    float* out = (float*)d_out;               // [B,I,D] fp32
    float* Wsum = (float*)d_ws;               // [I,J,D] fp32, 8 MiB (fits: proven r6)

    // Kernel A: IJ * D/4 = 524288 threads -> 2048 blocks of 256
    wsum_k<<<2048, 256, 0, stream>>>(W, Wsum);
    // Kernel B: one block per (b,i) = 8192 blocks of 128
    caps_k<<<B_SZ * I_CH, 128, 0, stream>>>(X, Wsum, out);
}

// Round 9
// 246.207 us; speedup vs baseline: 1.2939x; 1.2939x over previous
//
#include <hip/hip_runtime.h>

// out[b,i,d] = squash_d( sum_{j,k} X[b,j,d] * W[i,j,k,d] )
// B=128, I=64, J=32, K=16, D=1024. All fp32 (settled r8: PASS 2.44e-4).
// r8 counters: caps_k 121us, 1 TB/s HBM (12.5%), VALUBusy 7% -> bound on
// 2 GiB of redundant L2/L3 reads (each (b,i) block re-read full X[b],Wsum[i]).
// This round: 4x4 (b,i) register tiling in caps_k -> read traffic /4.
//   Wsum[i,j,d] = sum_k W[i,j,k,d]  (fp32, 8 MiB in d_ws)  [unchanged]
//   caps2_k: 512 blocks = 32 bGroups x 16 iGroups, 256 thr, 4 d/thread,
//            64 accumulators (4b x 4i x 4d), squash, fp32 out.

constexpr int B_SZ = 128, I_CH = 64, J_CH = 32, K_CAP = 16, D_DIM = 1024;

// Kernel A: Wsum[i,j,d] = sum_k W[i,j,k,d].  Unchanged from r8.
__global__ __launch_bounds__(256) void wsum_k(const float* __restrict__ W,
                                              float* __restrict__ Wsum) {
    int idx = blockIdx.x * 256 + threadIdx.x;   // over IJ * (D/4) = 2048*256
    int d4 = idx & 255;
    int ij = idx >> 8;
    const float4* Wv = (const float4*)(W + (size_t)ij * K_CAP * D_DIM) + d4;
    float4 acc = make_float4(0.f, 0.f, 0.f, 0.f);
#pragma unroll
    for (int k = 0; k < K_CAP; ++k) {
        float4 w = Wv[k * (D_DIM / 4)];
        acc.x += w.x; acc.y += w.y; acc.z += w.z; acc.w += w.w;
    }
    ((float4*)(Wsum + (size_t)ij * D_DIM))[d4] = acc;
}

// Kernel B v2: 4x4 (b,i) tile per block. 512 blocks x 256 threads.
// Thread t owns d in [t*4, t*4+4). Reads per block: 4 X-rows + 4 W-rows
// (1 MiB) for 16 output rows -> total read 512 MiB (was 2 GiB).
__global__ __launch_bounds__(256) void caps2_k(const float* __restrict__ X,
                                               const float* __restrict__ Wsum,
                                               float* __restrict__ out) {
    int t  = threadIdx.x;              // 0..255
    int ig = blockIdx.x & 15;          // i-group: i = ig*4 .. ig*4+3
    int bg = blockIdx.x >> 4;          // b-group: b = bg*4 .. bg*4+3
    const float* Xb = X    + (size_t)(bg * 4) * J_CH * D_DIM + t * 4;
    const float* Wb = Wsum + (size_t)(ig * 4) * J_CH * D_DIM + t * 4;

    float s[4][4][4];                  // [bb][ii][q]
#pragma unroll
    for (int bb = 0; bb < 4; ++bb)
#pragma unroll
        for (int ii = 0; ii < 4; ++ii)
#pragma unroll
            for (int q = 0; q < 4; ++q) s[bb][ii][q] = 0.f;

#pragma unroll 2
    for (int j = 0; j < J_CH; ++j) {
        float4 xv[4], wv[4];
#pragma unroll
        for (int bb = 0; bb < 4; ++bb)
            xv[bb] = *(const float4*)(Xb + (size_t)bb * J_CH * D_DIM + j * D_DIM);
#pragma unroll
        for (int ii = 0; ii < 4; ++ii)
            wv[ii] = *(const float4*)(Wb + (size_t)ii * J_CH * D_DIM + j * D_DIM);
#pragma unroll
        for (int bb = 0; bb < 4; ++bb)
#pragma unroll
            for (int ii = 0; ii < 4; ++ii) {
                s[bb][ii][0] += xv[bb].x * wv[ii].x;
                s[bb][ii][1] += xv[bb].y * wv[ii].y;
                s[bb][ii][2] += xv[bb].z * wv[ii].z;
                s[bb][ii][3] += xv[bb].w * wv[ii].w;
            }
    }

    // Per-(bb,ii) sum of squares over all 1024 d: wave shuffle + LDS combine.
    __shared__ float red[4][16];       // [wave][pair]
    __shared__ float scl[16];
    int lane = t & 63, wid = t >> 6;
#pragma unroll
    for (int p = 0; p < 16; ++p) {
        int bb = p >> 2, ii = p & 3;
        float ss = s[bb][ii][0] * s[bb][ii][0] + s[bb][ii][1] * s[bb][ii][1]
                 + s[bb][ii][2] * s[bb][ii][2] + s[bb][ii][3] * s[bb][ii][3];
#pragma unroll
        for (int off = 32; off > 0; off >>= 1) ss += __shfl_down(ss, off, 64);
        if (lane == 0) red[wid][p] = ss;
    }
    __syncthreads();
    if (t < 16) {
        float n2 = red[0][t] + red[1][t] + red[2][t] + red[3][t];
        float n  = sqrtf(n2);
        scl[t] = n2 / (1.0f + n2) / (n + 1e-8f);
    }
    __syncthreads();

#pragma unroll
    for (int bb = 0; bb < 4; ++bb)
#pragma unroll
        for (int ii = 0; ii < 4; ++ii) {
            float sc = scl[bb * 4 + ii];
            float4 o = make_float4(s[bb][ii][0] * sc, s[bb][ii][1] * sc,
                                   s[bb][ii][2] * sc, s[bb][ii][3] * sc);
            *(float4*)(out + ((size_t)(bg * 4 + bb) * I_CH + ig * 4 + ii) * D_DIM + t * 4) = o;
        }
}

extern "C" void kernel_launch(void* const* d_in, const int* in_sizes, int n_in,
                              void* d_out, int out_size, void* d_ws, size_t ws_size,
                              hipStream_t stream) {
    const float* X = (const float*)d_in[0];   // [B,J,D] fp32
    const float* W = (const float*)d_in[1];   // [I,J,K,D] fp32
    float* out = (float*)d_out;               // [B,I,D] fp32
    float* Wsum = (float*)d_ws;               // [I,J,D] fp32, 8 MiB

    wsum_k<<<2048, 256, 0, stream>>>(W, Wsum);
    caps2_k<<<(B_SZ / 4) * (I_CH / 4), 256, 0, stream>>>(X, Wsum, out);
}